// Round 7
// baseline (411.985 us; speedup 1.0000x reference)
//
#include <hip/hip_runtime.h>

// EntityLinker fused edge-MLP for MI355X (gfx950).
// Round 19: M=128 edges/block — amortize the weight stream + block overhead.
//   R18 post-mortem: 4th block/CU bought occupancy (33->44.6%) but dur was
//   flat (336->327us): per-CU block throughput is INVARIANT to resident
//   waves. No measured pipe is busy (MFMA 22%, VALU 24%, HBM 3.9%, LDS
//   conflicts 0.3%). The unmeasured per-CU cost scaling with block count:
//   each 64-edge block re-streams all 320KB of packed weights through
//   L1/L2 and pays 8 barriers of phase overhead. Fix: M=128 halves
//   weight-bytes/edge and halves block count (3907), at 2 blocks/CU
//   (acc[8][4]=128 AGPR, LDS 68.6KB) — a good trade since R18 showed
//   throughput doesn't care about occupancy.
//   Keeps: bf16 node cache, fragment-major packed weights, staged in-place
//   diff/prod, single-pointer weight bases, bias hoists, cheap cvt.

#define H 128

typedef __bf16 bf16x8 __attribute__((ext_vector_type(8)));
typedef float f32x4 __attribute__((ext_vector_type(4)));

__device__ __forceinline__ unsigned short f2bf(float f) {
    unsigned u = __builtin_bit_cast(unsigned, f);
    u += 0x7FFFu + ((u >> 16) & 1u);   // RNE
    return (unsigned short)(u >> 16);
}
__device__ __forceinline__ float bfhi(unsigned u) {
    return __builtin_bit_cast(float, u & 0xffff0000u);
}
__device__ __forceinline__ float bflo(unsigned u) {
    return __builtin_bit_cast(float, u << 16);
}
__device__ __forceinline__ unsigned pk2(float r0, float r1) {
    unsigned u0 = __builtin_bit_cast(unsigned, r0) + 0x8000u;
    unsigned u1 = __builtin_bit_cast(unsigned, r1) + 0x8000u;
    return __builtin_amdgcn_perm(u1, u0, 0x07060302u);
}
__device__ __forceinline__ unsigned comb(unsigned ua, unsigned ub, bool isdiff) {
    float a0 = bflo(ua), a1 = bfhi(ua);
    float b0 = bflo(ub), b1 = bfhi(ub);
    float r0 = isdiff ? fabsf(a0 - b0) : a0 * b0;
    float r1 = isdiff ? fabsf(a1 - b1) : a1 * b1;
    return pk2(r0, r1);
}
__device__ __forceinline__ unsigned short cvt1(float v) {
    unsigned u = __builtin_bit_cast(unsigned, v) + 0x8000u;
    return (unsigned short)(u >> 16);
}

__global__ void prep_node(const float* __restrict__ node, unsigned short* __restrict__ nbf) {
    int idx = blockIdx.x * 256 + threadIdx.x;      // N*H/4 threads, 4 elems each
    const f32x4* p = (const f32x4*)(node) + idx;
    f32x4 v = *p;
    ushort4 w;
    w.x = f2bf(v.x); w.y = f2bf(v.y); w.z = f2bf(v.z); w.w = f2bf(v.w);
    *(ushort4*)(nbf + idx * 4) = w;
}

// Fragment-major pack of W1 [512][256] (in,out):
//   W1P[o], o = (g_nt*16 + ks)*512 + lane*8 + j
//   row = g_nt*16 + (lane&15), k = ks*32 + (lane>>4)*8 + j
__global__ void prep_w1(const float* __restrict__ W1, unsigned short* __restrict__ W1P) {
    int o = blockIdx.x * 256 + threadIdx.x;        // 131072
    int chunk = o >> 9;
    int g_nt = chunk >> 4;
    int ks = chunk & 15;
    int r = o & 511;
    int lane = r >> 3;
    int j = r & 7;
    int row = g_nt * 16 + (lane & 15);
    int k = ks * 32 + (lane >> 4) * 8 + j;
    W1P[o] = f2bf(W1[k * 256 + row]);
}

// Fragment-major pack of W2 [256][128]:
//   W2P[o], o = (g_nt*8 + ks)*512 + lane*8 + j
__global__ void prep_w2(const float* __restrict__ W2, unsigned short* __restrict__ W2P) {
    int o = blockIdx.x * 256 + threadIdx.x;        // 32768
    int chunk = o >> 9;
    int g_nt = chunk >> 3;
    int ks = chunk & 7;
    int r = o & 511;
    int lane = r >> 3;
    int j = r & 7;
    int row = g_nt * 16 + (lane & 15);
    int k = ks * 32 + (lane >> 4) * 8 + j;
    W2P[o] = f2bf(W2[k * 128 + row]);
}

__launch_bounds__(256, 2)
__global__ void fused_mlp(const unsigned short* __restrict__ nbf,   // [N][128] bf16
                          const int* __restrict__ src,
                          const int* __restrict__ dst,
                          const unsigned short* __restrict__ W1P,  // packed
                          const float* __restrict__ b1,
                          const unsigned short* __restrict__ W2P,  // packed
                          const float* __restrict__ b2,
                          const float* __restrict__ W3,            // [128][2] f32
                          const float* __restrict__ b3,
                          float* __restrict__ out,                 // [E][2] f32
                          int E) {
    // sH: [128][268] bf16. Region P (cols 0..127): hi -> diff.
    //                      Region Q (cols 136..263): hj -> prod.
    // Overlays: x1 [128][268] cols 0..255; x2 [128][140].
    __shared__ __align__(16) unsigned short sH[128 * 268];   // 68608 B
    __shared__ __align__(16) float sW3[256];                 // [c][128]

    const int t = threadIdx.x;
    const int e0 = blockIdx.x * 128;

    const int lane = t & 63;
    const int wv = t >> 6;
    const int quad = lane >> 4;
    const int lrow = lane & 15;
    const int nb = wv * 64;        // layer-1 N-slice
    const int nb2 = wv * 32;       // layer-2 N-slice

    // Weight stream bases (single pointer + const offsets keeps arch-VGPR low).
    const unsigned short* w1b = W1P + wv * 32768 + lane * 8;   // wv*4*16*512
    const unsigned short* w2b = W2P + wv * 8192 + lane * 8;    // wv*2*8*512

    // ---------------- Phase A: gather hi/hj (bf16) -> LDS ----------------------
    {
        int r = t >> 1;            // edge row 0..127
        int q = t & 1;             // 64-col half (128 B)
        int e = e0 + r;
        int ec = e < E ? e : (E - 1);
        const unsigned short* hi = nbf + (long)src[ec] * H + q * 64;
        const unsigned short* hj = nbf + (long)dst[ec] * H + q * 64;
        unsigned short* rowp = sH + r * 268 + q * 64;
#pragma unroll
        for (int b = 0; b < 8; b++) {
            uint4 a = *(const uint4*)(hi + b * 8);
            uint4 c = *(const uint4*)(hj + b * 8);
            *(uint4*)(rowp + b * 8)       = a;
            *(uint4*)(rowp + 136 + b * 8) = c;
        }
        sW3[(t & 1) * 128 + (t >> 1)] = W3[t];   // [k][c] -> [c][k]
    }
    __syncthreads();               // hi/hj visible

    // ---------------- Phase B: layer 1 (M=128, N=256, K=512) ----------------
    f32x4 acc[8][4];
#pragma unroll
    for (int mt = 0; mt < 8; mt++)
#pragma unroll
        for (int nt = 0; nt < 4; nt++)
            acc[mt][nt] = (f32x4){0.f, 0.f, 0.f, 0.f};

    int aoff[8];
#pragma unroll
    for (int mt = 0; mt < 8; mt++) aoff[mt] = (mt * 16 + lrow) * 268 + quad * 8;

    // K-half 1: k 0..255  (A = hi | hj, as stored)
#pragma unroll 1
    for (int ks = 0; ks < 8; ks++) {
        const int ao = (ks < 4) ? ks * 32 : 136 + (ks - 4) * 32;
        bf16x8 bv[4];
#pragma unroll
        for (int nt = 0; nt < 4; nt++) bv[nt] = *(const bf16x8*)(w1b + nt * 8192 + ks * 512);
#pragma unroll
        for (int mt = 0; mt < 8; mt++) {
            bf16x8 av = *(const bf16x8*)(sH + aoff[mt] + ao);
#pragma unroll
            for (int nt = 0; nt < 4; nt++)
                acc[mt][nt] = __builtin_amdgcn_mfma_f32_16x16x32_bf16(av, bv[nt], acc[mt][nt], 0, 0, 0);
        }
    }

    // Hoisted: layer-1 bias (needed in Phase C).
    float b1v[4];
#pragma unroll
    for (int nt = 0; nt < 4; nt++) b1v[nt] = b1[nb + nt * 16 + lrow];

    __syncthreads();               // half-1 reads of hi/hj complete

    // ------------- Staging: diff -> region P, prod -> region Q (in place) -------
    {
        int r = t >> 1;
        int c0 = (t & 1) * 64;
        unsigned short* rowp = sH + r * 268;
#pragma unroll
        for (int j = 0; j < 8; j++) {
            uint4 ua = *(const uint4*)(rowp + c0 + j * 8);
            uint4 ub = *(const uint4*)(rowp + 136 + c0 + j * 8);
            uint4 dd, pp;
            dd.x = comb(ua.x, ub.x, true);  dd.y = comb(ua.y, ub.y, true);
            dd.z = comb(ua.z, ub.z, true);  dd.w = comb(ua.w, ub.w, true);
            pp.x = comb(ua.x, ub.x, false); pp.y = comb(ua.y, ub.y, false);
            pp.z = comb(ua.z, ub.z, false); pp.w = comb(ua.w, ub.w, false);
            *(uint2*)(rowp + c0 + j * 8)           = (uint2){dd.x, dd.y};
            *(uint2*)(rowp + c0 + j * 8 + 4)       = (uint2){dd.z, dd.w};
            *(uint2*)(rowp + 136 + c0 + j * 8)     = (uint2){pp.x, pp.y};
            *(uint2*)(rowp + 136 + c0 + j * 8 + 4) = (uint2){pp.z, pp.w};
        }
    }
    __syncthreads();               // diff/prod staged

    // K-half 2: k 256..511 (A = diff | prod, same addressing)
#pragma unroll 1
    for (int ks = 0; ks < 8; ks++) {
        const int ao = (ks < 4) ? ks * 32 : 136 + (ks - 4) * 32;
        bf16x8 bv[4];
#pragma unroll
        for (int nt = 0; nt < 4; nt++) bv[nt] = *(const bf16x8*)(w1b + nt * 8192 + (ks + 8) * 512);
#pragma unroll
        for (int mt = 0; mt < 8; mt++) {
            bf16x8 av = *(const bf16x8*)(sH + aoff[mt] + ao);
#pragma unroll
            for (int nt = 0; nt < 4; nt++)
                acc[mt][nt] = __builtin_amdgcn_mfma_f32_16x16x32_bf16(av, bv[nt], acc[mt][nt], 0, 0, 0);
        }
    }

    // Hoisted: layer-2 bias.
    float b2v[2];
#pragma unroll
    for (int nt = 0; nt < 2; nt++) b2v[nt] = b2[nb2 + nt * 16 + lrow];

    // ---------------- Phase C: relu+bias -> x1 bf16 (overlay sH) ----------------
    __syncthreads();               // all layer-1 reads of sH done
    unsigned short* sx1 = sH;      // [128][268], cols 0..255
#pragma unroll
    for (int mt = 0; mt < 8; mt++)
#pragma unroll
        for (int nt = 0; nt < 4; nt++)
#pragma unroll
            for (int i = 0; i < 4; i++) {
                int row = mt * 16 + quad * 4 + i;    // C/D: row = quad*4 + reg
                int col = nb + nt * 16 + lrow;       //      col = lane&15
                float v = acc[mt][nt][i] + b1v[nt];
                v = v > 0.f ? v : 0.f;
                sx1[row * 268 + col] = cvt1(v);
            }
    __syncthreads();               // x1 complete

    // ---------------- Phase D: layer 2 (M=128, N=128, K=256) ----------------
    f32x4 acc2[8][2];
#pragma unroll
    for (int mt = 0; mt < 8; mt++)
#pragma unroll
        for (int nt = 0; nt < 2; nt++)
            acc2[mt][nt] = (f32x4){0.f, 0.f, 0.f, 0.f};

#pragma unroll 1
    for (int ks = 0; ks < 8; ks++) {
        bf16x8 bv2[2];
#pragma unroll
        for (int nt = 0; nt < 2; nt++) bv2[nt] = *(const bf16x8*)(w2b + nt * 4096 + ks * 512);
#pragma unroll
        for (int mt = 0; mt < 8; mt++) {
            bf16x8 av2 = *(const bf16x8*)(sx1 + aoff[mt] + ks * 32);
#pragma unroll
            for (int nt = 0; nt < 2; nt++)
                acc2[mt][nt] = __builtin_amdgcn_mfma_f32_16x16x32_bf16(av2, bv2[nt], acc2[mt][nt], 0, 0, 0);
        }
    }

    // ---------------- Phase E: relu+bias -> x2 bf16 (overlay) ----------------
    __syncthreads();               // all layer-2 reads of x1 done
    unsigned short* sx2 = sH;      // [128][140] (70 dw stride, gcd 2 -> free)
#pragma unroll
    for (int mt = 0; mt < 8; mt++)
#pragma unroll
        for (int nt = 0; nt < 2; nt++)
#pragma unroll
            for (int i = 0; i < 4; i++) {
                int row = mt * 16 + quad * 4 + i;
                int col = nb2 + nt * 16 + lrow;
                float v = acc2[mt][nt][i] + b2v[nt];
                v = v > 0.f ? v : 0.f;
                sx2[row * 140 + col] = cvt1(v);
            }
    __syncthreads();

    // ---------------- Phase F: layer 3 (N=2), full dot per thread ----------------
    {
        int r = t >> 1;            // edge row 0..127
        int c = t & 1;             // class
        const unsigned short* xr = sx2 + r * 140;
        const float* w3c = sW3 + c * 128;
        float s = 0.f;
#pragma unroll
        for (int j = 0; j < 16; j++) {
            uint4 v = *(const uint4*)(xr + j * 8);
            const float* w = w3c + j * 8;
            s += bflo(v.x) * w[0] + bfhi(v.x) * w[1]
               + bflo(v.y) * w[2] + bfhi(v.y) * w[3]
               + bflo(v.z) * w[4] + bfhi(v.z) * w[5]
               + bflo(v.w) * w[6] + bfhi(v.w) * w[7];
        }
        int e = e0 + r;
        if (e < E) out[e * 2 + c] = s + b3[c];
    }
}

extern "C" void kernel_launch(void* const* d_in, const int* in_sizes, int n_in,
                              void* d_out, int out_size, void* d_ws, size_t ws_size,
                              hipStream_t stream) {
    const float* node = (const float*)d_in[0];
    const int* src    = (const int*)d_in[1];
    const int* dst    = (const int*)d_in[2];
    const float* W1   = (const float*)d_in[3];
    const float* b1   = (const float*)d_in[4];
    const float* W2   = (const float*)d_in[5];
    const float* b2   = (const float*)d_in[6];
    const float* W3   = (const float*)d_in[7];
    const float* b3   = (const float*)d_in[8];
    float* out = (float*)d_out;
    const int NN = in_sizes[0] / H;                    // 50000 nodes
    const int E = in_sizes[1];

    unsigned short* W1P = (unsigned short*)d_ws;       // packed W1, 256 KiB
    unsigned short* W2P = W1P + 512 * 256;             // packed W2, 64 KiB
    unsigned short* NBF = W2P + 256 * 128;             // [N][128] bf16, 12.8 MB

    hipLaunchKernelGGL(prep_node, dim3((NN * H / 4 + 255) / 256), dim3(256), 0, stream, node, NBF);
    hipLaunchKernelGGL(prep_w1, dim3(512), dim3(256), 0, stream, W1, W1P);
    hipLaunchKernelGGL(prep_w2, dim3(128), dim3(256), 0, stream, W2, W2P);
    const int nblk = (E + 127) / 128;
    hipLaunchKernelGGL(fused_mlp, dim3(nblk), dim3(256), 0, stream,
                       NBF, src, dst, W1P, b1, W2P, b2, W3, b3, out, E);
}

// Round 15
// 381.059 us; speedup vs baseline: 1.0812x; 1.0812x over previous
//
#include <hip/hip_runtime.h>

// EntityLinker fused edge-MLP for MI355X (gfx950).
// Round 24..27 (resubmit — infra failed 3x on this variant, never measured):
// ROLLBACK to R18 (known-good, 327us dispatch) + differential test.
//   R20 post-mortem: register-staged diff/prod variant FAILED the replay
//   tripwire (run 1 correct, runs 2+ consistently diverged 1.40). Source
//   audit found no barrier/mapping bug; suspect is the dd/pp register
//   lifetime across K-half-1 under the (256,3) cap, or (improbably) the
//   Phase-F vector LDS reads. Rollback per rigor.md; keep ONLY the Phase-F
//   sW3 f32x4 vectorization (mapping-identical to R18 scalars, no barrier
//   or lifetime changes, 16B-aligned) as a differential probe: pass =>
//   R20's bug was the register staging; fail => vector reads implicated.
//   Session status: R13 (SW pipelining) null, R18 (occupancy 33->44%) null,
//   R19 (M=128 tile) regressed, R20 broken. 21% MfmaUtil / 4% HBM with
//   ~55% unexplained stall = structural plateau; remaining levers are
//   high-risk rewrites not submitted blind under infra flakiness.
//   Keeps (R18): 4 blocks/CU config, bf16 node cache, fragment-major
//   packed weights, staged in-place diff/prod, single-pointer weight
//   bases, bias hoists, 16x16 MFMA, cheap cvt.

#define H 128

typedef __bf16 bf16x8 __attribute__((ext_vector_type(8)));
typedef float f32x4 __attribute__((ext_vector_type(4)));

__device__ __forceinline__ unsigned short f2bf(float f) {
    unsigned u = __builtin_bit_cast(unsigned, f);
    u += 0x7FFFu + ((u >> 16) & 1u);   // RNE
    return (unsigned short)(u >> 16);
}
__device__ __forceinline__ float bfhi(unsigned u) {
    return __builtin_bit_cast(float, u & 0xffff0000u);
}
__device__ __forceinline__ float bflo(unsigned u) {
    return __builtin_bit_cast(float, u << 16);
}
__device__ __forceinline__ unsigned pk2(float r0, float r1) {
    unsigned u0 = __builtin_bit_cast(unsigned, r0) + 0x8000u;
    unsigned u1 = __builtin_bit_cast(unsigned, r1) + 0x8000u;
    return __builtin_amdgcn_perm(u1, u0, 0x07060302u);
}
__device__ __forceinline__ unsigned comb(unsigned ua, unsigned ub, bool isdiff) {
    float a0 = bflo(ua), a1 = bfhi(ua);
    float b0 = bflo(ub), b1 = bfhi(ub);
    float r0 = isdiff ? fabsf(a0 - b0) : a0 * b0;
    float r1 = isdiff ? fabsf(a1 - b1) : a1 * b1;
    return pk2(r0, r1);
}
__device__ __forceinline__ unsigned short cvt1(float v) {
    unsigned u = __builtin_bit_cast(unsigned, v) + 0x8000u;
    return (unsigned short)(u >> 16);
}

__global__ void prep_node(const float* __restrict__ node, unsigned short* __restrict__ nbf) {
    int idx = blockIdx.x * 256 + threadIdx.x;      // N*H/4 threads, 4 elems each
    const f32x4* p = (const f32x4*)(node) + idx;
    f32x4 v = *p;
    ushort4 w;
    w.x = f2bf(v.x); w.y = f2bf(v.y); w.z = f2bf(v.z); w.w = f2bf(v.w);
    *(ushort4*)(nbf + idx * 4) = w;
}

// Fragment-major pack of W1 [512][256] (in,out):
//   W1P[o], o = (g_nt*16 + ks)*512 + lane*8 + j
//   row = g_nt*16 + (lane&15), k = ks*32 + (lane>>4)*8 + j
__global__ void prep_w1(const float* __restrict__ W1, unsigned short* __restrict__ W1P) {
    int o = blockIdx.x * 256 + threadIdx.x;        // 131072
    int chunk = o >> 9;
    int g_nt = chunk >> 4;
    int ks = chunk & 15;
    int r = o & 511;
    int lane = r >> 3;
    int j = r & 7;
    int row = g_nt * 16 + (lane & 15);
    int k = ks * 32 + (lane >> 4) * 8 + j;
    W1P[o] = f2bf(W1[k * 256 + row]);
}

// Fragment-major pack of W2 [256][128]:
//   W2P[o], o = (g_nt*8 + ks)*512 + lane*8 + j
__global__ void prep_w2(const float* __restrict__ W2, unsigned short* __restrict__ W2P) {
    int o = blockIdx.x * 256 + threadIdx.x;        // 32768
    int chunk = o >> 9;
    int g_nt = chunk >> 3;
    int ks = chunk & 7;
    int r = o & 511;
    int lane = r >> 3;
    int j = r & 7;
    int row = g_nt * 16 + (lane & 15);
    int k = ks * 32 + (lane >> 4) * 8 + j;
    W2P[o] = f2bf(W2[k * 128 + row]);
}

__launch_bounds__(256, 4)
__global__ void fused_mlp(const unsigned short* __restrict__ nbf,   // [N][128] bf16
                          const int* __restrict__ src,
                          const int* __restrict__ dst,
                          const unsigned short* __restrict__ W1P,  // packed
                          const float* __restrict__ b1,
                          const unsigned short* __restrict__ W2P,  // packed
                          const float* __restrict__ b2,
                          const float* __restrict__ W3,            // [128][2] f32
                          const float* __restrict__ b3,
                          float* __restrict__ out,                 // [E][2] f32
                          int E) {
    // sH: [64][268] bf16. Region P (cols 0..127): hi -> diff.
    //                     Region Q (cols 136..263): hj -> prod.
    // Overlays: x1 [64][268] cols 0..255; x2 [64][140].
    __shared__ __align__(16) unsigned short sH[64 * 268];    // 34304 B
    __shared__ __align__(16) float sW3[256];                 // [c][128]

    const int t = threadIdx.x;
    const int e0 = blockIdx.x * 64;

    const int lane = t & 63;
    const int wv = t >> 6;
    const int quad = lane >> 4;
    const int lrow = lane & 15;
    const int nb = wv * 64;        // layer-1 N-slice
    const int nb2 = wv * 32;       // layer-2 N-slice

    // Weight stream bases (single pointer + const offsets keeps arch-VGPR
    // use low; the unified budget must stay <=128 for 4 waves/SIMD).
    const unsigned short* w1b = W1P + wv * 32768 + lane * 8;   // wv*4*16*512
    const unsigned short* w2b = W2P + wv * 8192 + lane * 8;    // wv*2*8*512

    // ---------------- Phase A: gather hi/hj (bf16) -> LDS, line-granular --------
    {
        int r = t >> 2;            // edge row 0..63
        int q = t & 3;             // 32-col quarter (64 B = one cache line)
        int e = e0 + r;
        int ec = e < E ? e : (E - 1);
        const unsigned short* hi = nbf + (long)src[ec] * H + q * 32;
        const unsigned short* hj = nbf + (long)dst[ec] * H + q * 32;
        unsigned short* rowp = sH + r * 268 + q * 32;
#pragma unroll
        for (int b = 0; b < 4; b++) {
            uint4 a = *(const uint4*)(hi + b * 8);
            uint4 c = *(const uint4*)(hj + b * 8);
            *(uint4*)(rowp + b * 8)       = a;
            *(uint4*)(rowp + 136 + b * 8) = c;
        }
        sW3[(t & 1) * 128 + (t >> 1)] = W3[t];   // [k][c] -> [c][k]
    }
    __syncthreads();               // hi/hj visible

    // ---------------- Phase B: layer 1 (M=64, N=256, K=512) ----------------
    f32x4 acc[4][4];
#pragma unroll
    for (int mt = 0; mt < 4; mt++)
#pragma unroll
        for (int nt = 0; nt < 4; nt++)
            acc[mt][nt] = (f32x4){0.f, 0.f, 0.f, 0.f};

    int aoff[4];
#pragma unroll
    for (int mt = 0; mt < 4; mt++) aoff[mt] = (mt * 16 + lrow) * 268 + quad * 8;

    // K-half 1: k 0..255  (A = hi | hj, as stored)
#pragma unroll 1
    for (int ks = 0; ks < 8; ks++) {
        const int ao = (ks < 4) ? ks * 32 : 136 + (ks - 4) * 32;
        bf16x8 bv[4], av[4];
#pragma unroll
        for (int nt = 0; nt < 4; nt++) bv[nt] = *(const bf16x8*)(w1b + nt * 8192 + ks * 512);
#pragma unroll
        for (int mt = 0; mt < 4; mt++) av[mt] = *(const bf16x8*)(sH + aoff[mt] + ao);
#pragma unroll
        for (int mt = 0; mt < 4; mt++)
#pragma unroll
            for (int nt = 0; nt < 4; nt++)
                acc[mt][nt] = __builtin_amdgcn_mfma_f32_16x16x32_bf16(av[mt], bv[nt], acc[mt][nt], 0, 0, 0);
    }

    // Hoisted: layer-1 bias (needed in Phase C; load covered by half-2 loop).
    float b1v[4];
#pragma unroll
    for (int nt = 0; nt < 4; nt++) b1v[nt] = b1[nb + nt * 16 + lrow];

    __syncthreads();               // half-1 reads of hi/hj complete

    // ------------- Staging: diff -> region P, prod -> region Q (in place) -------
    {
        int r = t >> 2;
        int c0 = (t & 3) * 32;
        unsigned short* rowp = sH + r * 268;
#pragma unroll
        for (int j = 0; j < 4; j++) {
            uint4 ua = *(const uint4*)(rowp + c0 + j * 8);
            uint4 ub = *(const uint4*)(rowp + 136 + c0 + j * 8);
            uint4 dd, pp;
            dd.x = comb(ua.x, ub.x, true);  dd.y = comb(ua.y, ub.y, true);
            dd.z = comb(ua.z, ub.z, true);  dd.w = comb(ua.w, ub.w, true);
            pp.x = comb(ua.x, ub.x, false); pp.y = comb(ua.y, ub.y, false);
            pp.z = comb(ua.z, ub.z, false); pp.w = comb(ua.w, ub.w, false);
            *(uint2*)(rowp + c0 + j * 8)           = (uint2){dd.x, dd.y};
            *(uint2*)(rowp + c0 + j * 8 + 4)       = (uint2){dd.z, dd.w};
            *(uint2*)(rowp + 136 + c0 + j * 8)     = (uint2){pp.x, pp.y};
            *(uint2*)(rowp + 136 + c0 + j * 8 + 4) = (uint2){pp.z, pp.w};
        }
    }
    __syncthreads();               // diff/prod staged

    // K-half 2: k 256..511 (A = diff | prod, same addressing)
#pragma unroll 1
    for (int ks = 0; ks < 8; ks++) {
        const int ao = (ks < 4) ? ks * 32 : 136 + (ks - 4) * 32;
        bf16x8 bv[4], av[4];
#pragma unroll
        for (int nt = 0; nt < 4; nt++) bv[nt] = *(const bf16x8*)(w1b + nt * 8192 + (ks + 8) * 512);
#pragma unroll
        for (int mt = 0; mt < 4; mt++) av[mt] = *(const bf16x8*)(sH + aoff[mt] + ao);
#pragma unroll
        for (int mt = 0; mt < 4; mt++)
#pragma unroll
            for (int nt = 0; nt < 4; nt++)
                acc[mt][nt] = __builtin_amdgcn_mfma_f32_16x16x32_bf16(av[mt], bv[nt], acc[mt][nt], 0, 0, 0);
    }

    // Hoisted: layer-2 bias — latency covered by Phase C.
    float b2v[2];
#pragma unroll
    for (int nt = 0; nt < 2; nt++) b2v[nt] = b2[nb2 + nt * 16 + lrow];

    // ---------------- Phase C: relu+bias -> x1 bf16 (overlay sH) ----------------
    __syncthreads();               // all layer-1 reads of sH done
    unsigned short* sx1 = sH;      // [64][268], cols 0..255
#pragma unroll
    for (int mt = 0; mt < 4; mt++)
#pragma unroll
        for (int nt = 0; nt < 4; nt++)
#pragma unroll
            for (int i = 0; i < 4; i++) {
                int row = mt * 16 + quad * 4 + i;    // C/D: row = quad*4 + reg
                int col = nb + nt * 16 + lrow;       //      col = lane&15
                float v = acc[mt][nt][i] + b1v[nt];
                v = v > 0.f ? v : 0.f;
                sx1[row * 268 + col] = cvt1(v);
            }
    __syncthreads();               // x1 complete

    // ---------------- Phase D: layer 2 (M=64, N=128, K=256) ----------------
    f32x4 acc2[4][2];
#pragma unroll
    for (int mt = 0; mt < 4; mt++)
#pragma unroll
        for (int nt = 0; nt < 2; nt++)
            acc2[mt][nt] = (f32x4){0.f, 0.f, 0.f, 0.f};

#pragma unroll 1
    for (int ks = 0; ks < 8; ks++) {
        bf16x8 bv2[2], av2[4];
#pragma unroll
        for (int nt = 0; nt < 2; nt++) bv2[nt] = *(const bf16x8*)(w2b + nt * 4096 + ks * 512);
#pragma unroll
        for (int mt = 0; mt < 4; mt++) av2[mt] = *(const bf16x8*)(sx1 + aoff[mt] + ks * 32);
#pragma unroll
        for (int mt = 0; mt < 4; mt++)
#pragma unroll
            for (int nt = 0; nt < 2; nt++)
                acc2[mt][nt] = __builtin_amdgcn_mfma_f32_16x16x32_bf16(av2[mt], bv2[nt], acc2[mt][nt], 0, 0, 0);
    }

    // ---------------- Phase E: relu+bias -> x2 bf16 (overlay) ----------------
    __syncthreads();               // all layer-2 reads of x1 done
    unsigned short* sx2 = sH;      // [64][140] (70 dw stride, gcd 2 -> free)
#pragma unroll
    for (int mt = 0; mt < 4; mt++)
#pragma unroll
        for (int nt = 0; nt < 2; nt++)
#pragma unroll
            for (int i = 0; i < 4; i++) {
                int row = mt * 16 + quad * 4 + i;
                int col = nb2 + nt * 16 + lrow;
                float v = acc2[mt][nt][i] + b2v[nt];
                v = v > 0.f ? v : 0.f;
                sx2[row * 140 + col] = cvt1(v);
            }
    __syncthreads();

    // ---------------- Phase F: layer 3 (N=2), half-dots + shfl ----------------
    // (R20's safe half: sW3 reads vectorized f32x4 — 16B-aligned: offsets
    //  c*512 + h*256 + j*32 (+16) bytes from a 16B-aligned base.)
    {
        int r = t >> 2;            // edge row 0..63
        int c = t & 1;             // class
        int h = (t >> 1) & 1;      // K-half
        const unsigned short* xr = sx2 + r * 140 + h * 64;
        const float* w3c = sW3 + c * 128 + h * 64;
        float s = 0.f;
#pragma unroll
        for (int j = 0; j < 8; j++) {
            uint4 v = *(const uint4*)(xr + j * 8);
            f32x4 w0 = *(const f32x4*)(w3c + j * 8);
            f32x4 w1 = *(const f32x4*)(w3c + j * 8 + 4);
            s += bflo(v.x) * w0[0] + bfhi(v.x) * w0[1]
               + bflo(v.y) * w0[2] + bfhi(v.y) * w0[3]
               + bflo(v.z) * w1[0] + bfhi(v.z) * w1[1]
               + bflo(v.w) * w1[2] + bfhi(v.w) * w1[3];
        }
        s += __shfl_xor(s, 2);     // combine K-halves
        int e = e0 + r;
        if (h == 0 && e < E) out[e * 2 + c] = s + b3[c];
    }
}

extern "C" void kernel_launch(void* const* d_in, const int* in_sizes, int n_in,
                              void* d_out, int out_size, void* d_ws, size_t ws_size,
                              hipStream_t stream) {
    const float* node = (const float*)d_in[0];
    const int* src    = (const int*)d_in[1];
    const int* dst    = (const int*)d_in[2];
    const float* W1   = (const float*)d_in[3];
    const float* b1   = (const float*)d_in[4];
    const float* W2   = (const float*)d_in[5];
    const float* b2   = (const float*)d_in[6];
    const float* W3   = (const float*)d_in[7];
    const float* b3   = (const float*)d_in[8];
    float* out = (float*)d_out;
    const int NN = in_sizes[0] / H;                    // 50000 nodes
    const int E = in_sizes[1];

    unsigned short* W1P = (unsigned short*)d_ws;       // packed W1, 256 KiB
    unsigned short* W2P = W1P + 512 * 256;             // packed W2, 64 KiB
    unsigned short* NBF = W2P + 256 * 128;             // [N][128] bf16, 12.8 MB

    hipLaunchKernelGGL(prep_node, dim3((NN * H / 4 + 255) / 256), dim3(256), 0, stream, node, NBF);
    hipLaunchKernelGGL(prep_w1, dim3(512), dim3(256), 0, stream, W1, W1P);
    hipLaunchKernelGGL(prep_w2, dim3(128), dim3(256), 0, stream, W2, W2P);
    const int nblk = (E + 63) / 64;
    hipLaunchKernelGGL(fused_mlp, dim3(nblk), dim3(256), 0, stream,
                       NBF, src, dst, W1P, b1, W2P, b2, W3, b3, out, E);
}

// Round 17
// 359.209 us; speedup vs baseline: 1.1469x; 1.0608x over previous
//
#include <hip/hip_runtime.h>

// EntityLinker fused edge-MLP for MI355X (gfx950).
// Round 28/29 (resubmit — infra failed, never measured):
// delete the staging phase — on-the-fly diff/prod in K-half-2.
//   R24 post-mortem: differential PASSED (327.6us == R18's 327.4; Phase-F
//   vector LDS reads innocent; R20's bug was the cross-phase register
//   lifetime). Convoy/barrier theory still unmeasured -> test it safely:
//   a diff A-fragment at (row,k) = comb(hi_frag, hj_frag) at the SAME
//   position, so K-half-2 can read hi+hj pairs (8 vs 4 reads/iter) from
//   the untouched P/Q regions and combine in registers (bit-identical
//   comb -> identical output). This deletes the staging phase AND both
//   its barriers (7 -> 5); layer-1 is one barrier-free 16-step K-loop.
//   Unlike R20: no in-place overwrite, no register lifetime across any
//   barrier. Cost: ~1400 VALU/wave on an idle pipe (VALUBusy 24->~35).
//   Predict: dur 327 -> 290-310 if phase serialization is the stall;
//   flat => plateau is intrinsic, declare next round.
//   Keeps (R24): 4 blocks/CU, bf16 node cache, fragment-major packed
//   weights, single-pointer weight bases, bias hoists, vectorized sW3.

#define H 128

typedef __bf16 bf16x8 __attribute__((ext_vector_type(8)));
typedef float f32x4 __attribute__((ext_vector_type(4)));

__device__ __forceinline__ unsigned short f2bf(float f) {
    unsigned u = __builtin_bit_cast(unsigned, f);
    u += 0x7FFFu + ((u >> 16) & 1u);   // RNE
    return (unsigned short)(u >> 16);
}
__device__ __forceinline__ float bfhi(unsigned u) {
    return __builtin_bit_cast(float, u & 0xffff0000u);
}
__device__ __forceinline__ float bflo(unsigned u) {
    return __builtin_bit_cast(float, u << 16);
}
__device__ __forceinline__ unsigned pk2(float r0, float r1) {
    unsigned u0 = __builtin_bit_cast(unsigned, r0) + 0x8000u;
    unsigned u1 = __builtin_bit_cast(unsigned, r1) + 0x8000u;
    return __builtin_amdgcn_perm(u1, u0, 0x07060302u);
}
__device__ __forceinline__ unsigned comb(unsigned ua, unsigned ub, bool isdiff) {
    float a0 = bflo(ua), a1 = bfhi(ua);
    float b0 = bflo(ub), b1 = bfhi(ub);
    float r0 = isdiff ? fabsf(a0 - b0) : a0 * b0;
    float r1 = isdiff ? fabsf(a1 - b1) : a1 * b1;
    return pk2(r0, r1);
}
__device__ __forceinline__ unsigned short cvt1(float v) {
    unsigned u = __builtin_bit_cast(unsigned, v) + 0x8000u;
    return (unsigned short)(u >> 16);
}

__global__ void prep_node(const float* __restrict__ node, unsigned short* __restrict__ nbf) {
    int idx = blockIdx.x * 256 + threadIdx.x;      // N*H/4 threads, 4 elems each
    const f32x4* p = (const f32x4*)(node) + idx;
    f32x4 v = *p;
    ushort4 w;
    w.x = f2bf(v.x); w.y = f2bf(v.y); w.z = f2bf(v.z); w.w = f2bf(v.w);
    *(ushort4*)(nbf + idx * 4) = w;
}

// Fragment-major pack of W1 [512][256] (in,out):
//   W1P[o], o = (g_nt*16 + ks)*512 + lane*8 + j
//   row = g_nt*16 + (lane&15), k = ks*32 + (lane>>4)*8 + j
__global__ void prep_w1(const float* __restrict__ W1, unsigned short* __restrict__ W1P) {
    int o = blockIdx.x * 256 + threadIdx.x;        // 131072
    int chunk = o >> 9;
    int g_nt = chunk >> 4;
    int ks = chunk & 15;
    int r = o & 511;
    int lane = r >> 3;
    int j = r & 7;
    int row = g_nt * 16 + (lane & 15);
    int k = ks * 32 + (lane >> 4) * 8 + j;
    W1P[o] = f2bf(W1[k * 256 + row]);
}

// Fragment-major pack of W2 [256][128]:
//   W2P[o], o = (g_nt*8 + ks)*512 + lane*8 + j
__global__ void prep_w2(const float* __restrict__ W2, unsigned short* __restrict__ W2P) {
    int o = blockIdx.x * 256 + threadIdx.x;        // 32768
    int chunk = o >> 9;
    int g_nt = chunk >> 3;
    int ks = chunk & 7;
    int r = o & 511;
    int lane = r >> 3;
    int j = r & 7;
    int row = g_nt * 16 + (lane & 15);
    int k = ks * 32 + (lane >> 4) * 8 + j;
    W2P[o] = f2bf(W2[k * 128 + row]);
}

__launch_bounds__(256, 4)
__global__ void fused_mlp(const unsigned short* __restrict__ nbf,   // [N][128] bf16
                          const int* __restrict__ src,
                          const int* __restrict__ dst,
                          const unsigned short* __restrict__ W1P,  // packed
                          const float* __restrict__ b1,
                          const unsigned short* __restrict__ W2P,  // packed
                          const float* __restrict__ b2,
                          const float* __restrict__ W3,            // [128][2] f32
                          const float* __restrict__ b3,
                          float* __restrict__ out,                 // [E][2] f32
                          int E) {
    // sH: [64][268] bf16. Region P (cols 0..127): hi (never overwritten
    //     during layer 1). Region Q (cols 136..263): hj.
    // Overlays: x1 [64][268] cols 0..255 (after barrier); x2 [64][140].
    __shared__ __align__(16) unsigned short sH[64 * 268];    // 34304 B
    __shared__ __align__(16) float sW3[256];                 // [c][128]

    const int t = threadIdx.x;
    const int e0 = blockIdx.x * 64;

    const int lane = t & 63;
    const int wv = t >> 6;
    const int quad = lane >> 4;
    const int lrow = lane & 15;
    const int nb = wv * 64;        // layer-1 N-slice
    const int nb2 = wv * 32;       // layer-2 N-slice

    // Weight stream bases (single pointer + const offsets keeps arch-VGPR
    // use low; the unified budget must stay <=128 for 4 waves/SIMD).
    const unsigned short* w1b = W1P + wv * 32768 + lane * 8;   // wv*4*16*512
    const unsigned short* w2b = W2P + wv * 8192 + lane * 8;    // wv*2*8*512

    // ---------------- Phase A: gather hi/hj (bf16) -> LDS, line-granular --------
    {
        int r = t >> 2;            // edge row 0..63
        int q = t & 3;             // 32-col quarter (64 B = one cache line)
        int e = e0 + r;
        int ec = e < E ? e : (E - 1);
        const unsigned short* hi = nbf + (long)src[ec] * H + q * 32;
        const unsigned short* hj = nbf + (long)dst[ec] * H + q * 32;
        unsigned short* rowp = sH + r * 268 + q * 32;
#pragma unroll
        for (int b = 0; b < 4; b++) {
            uint4 a = *(const uint4*)(hi + b * 8);
            uint4 c = *(const uint4*)(hj + b * 8);
            *(uint4*)(rowp + b * 8)       = a;
            *(uint4*)(rowp + 136 + b * 8) = c;
        }
        sW3[(t & 1) * 128 + (t >> 1)] = W3[t];   // [k][c] -> [c][k]
    }
    __syncthreads();               // hi/hj visible

    // ---------------- Phase B: layer 1 (M=64, N=256, K=512), barrier-free -------
    f32x4 acc[4][4];
#pragma unroll
    for (int mt = 0; mt < 4; mt++)
#pragma unroll
        for (int nt = 0; nt < 4; nt++)
            acc[mt][nt] = (f32x4){0.f, 0.f, 0.f, 0.f};

    int aoff[4];
#pragma unroll
    for (int mt = 0; mt < 4; mt++) aoff[mt] = (mt * 16 + lrow) * 268 + quad * 8;

    // K-half 1: k 0..255  (A = hi | hj, as stored)
#pragma unroll 1
    for (int ks = 0; ks < 8; ks++) {
        const int ao = (ks < 4) ? ks * 32 : 136 + (ks - 4) * 32;
        bf16x8 bv[4], av[4];
#pragma unroll
        for (int nt = 0; nt < 4; nt++) bv[nt] = *(const bf16x8*)(w1b + nt * 8192 + ks * 512);
#pragma unroll
        for (int mt = 0; mt < 4; mt++) av[mt] = *(const bf16x8*)(sH + aoff[mt] + ao);
#pragma unroll
        for (int mt = 0; mt < 4; mt++)
#pragma unroll
            for (int nt = 0; nt < 4; nt++)
                acc[mt][nt] = __builtin_amdgcn_mfma_f32_16x16x32_bf16(av[mt], bv[nt], acc[mt][nt], 0, 0, 0);
    }

    // K-half 2a: k 256..383 (A = diff), fragments combined on the fly from
    // hi (P region) and hj (Q region) at the same (row, k-slice) — comb is
    // bit-identical to the old staged path. No staging, no barriers.
#pragma unroll 1
    for (int ks = 0; ks < 4; ks++) {
        bf16x8 bv[4];
#pragma unroll
        for (int nt = 0; nt < 4; nt++) bv[nt] = *(const bf16x8*)(w1b + nt * 8192 + (ks + 8) * 512);
#pragma unroll
        for (int mt = 0; mt < 4; mt++) {
            uint4 hu = *(const uint4*)(sH + aoff[mt] + ks * 32);
            uint4 ju = *(const uint4*)(sH + aoff[mt] + 136 + ks * 32);
            uint4 cv;
            cv.x = comb(hu.x, ju.x, true);  cv.y = comb(hu.y, ju.y, true);
            cv.z = comb(hu.z, ju.z, true);  cv.w = comb(hu.w, ju.w, true);
            bf16x8 av = __builtin_bit_cast(bf16x8, cv);
#pragma unroll
            for (int nt = 0; nt < 4; nt++)
                acc[mt][nt] = __builtin_amdgcn_mfma_f32_16x16x32_bf16(av, bv[nt], acc[mt][nt], 0, 0, 0);
        }
    }

    // K-half 2b: k 384..511 (A = prod), same scheme.
#pragma unroll 1
    for (int ks = 0; ks < 4; ks++) {
        bf16x8 bv[4];
#pragma unroll
        for (int nt = 0; nt < 4; nt++) bv[nt] = *(const bf16x8*)(w1b + nt * 8192 + (ks + 12) * 512);
#pragma unroll
        for (int mt = 0; mt < 4; mt++) {
            uint4 hu = *(const uint4*)(sH + aoff[mt] + ks * 32);
            uint4 ju = *(const uint4*)(sH + aoff[mt] + 136 + ks * 32);
            uint4 cv;
            cv.x = comb(hu.x, ju.x, false); cv.y = comb(hu.y, ju.y, false);
            cv.z = comb(hu.z, ju.z, false); cv.w = comb(hu.w, ju.w, false);
            bf16x8 av = __builtin_bit_cast(bf16x8, cv);
#pragma unroll
            for (int nt = 0; nt < 4; nt++)
                acc[mt][nt] = __builtin_amdgcn_mfma_f32_16x16x32_bf16(av, bv[nt], acc[mt][nt], 0, 0, 0);
        }
    }

    // Hoisted: biases (needed in Phases C/E).
    float b1v[4];
#pragma unroll
    for (int nt = 0; nt < 4; nt++) b1v[nt] = b1[nb + nt * 16 + lrow];
    float b2v[2];
#pragma unroll
    for (int nt = 0; nt < 2; nt++) b2v[nt] = b2[nb2 + nt * 16 + lrow];

    // ---------------- Phase C: relu+bias -> x1 bf16 (overlay sH) ----------------
    __syncthreads();               // all layer-1 reads of sH done
    unsigned short* sx1 = sH;      // [64][268], cols 0..255
#pragma unroll
    for (int mt = 0; mt < 4; mt++)
#pragma unroll
        for (int nt = 0; nt < 4; nt++)
#pragma unroll
            for (int i = 0; i < 4; i++) {
                int row = mt * 16 + quad * 4 + i;    // C/D: row = quad*4 + reg
                int col = nb + nt * 16 + lrow;       //      col = lane&15
                float v = acc[mt][nt][i] + b1v[nt];
                v = v > 0.f ? v : 0.f;
                sx1[row * 268 + col] = cvt1(v);
            }
    __syncthreads();               // x1 complete

    // ---------------- Phase D: layer 2 (M=64, N=128, K=256) ----------------
    f32x4 acc2[4][2];
#pragma unroll
    for (int mt = 0; mt < 4; mt++)
#pragma unroll
        for (int nt = 0; nt < 2; nt++)
            acc2[mt][nt] = (f32x4){0.f, 0.f, 0.f, 0.f};

#pragma unroll 1
    for (int ks = 0; ks < 8; ks++) {
        bf16x8 bv2[2], av2[4];
#pragma unroll
        for (int nt = 0; nt < 2; nt++) bv2[nt] = *(const bf16x8*)(w2b + nt * 4096 + ks * 512);
#pragma unroll
        for (int mt = 0; mt < 4; mt++) av2[mt] = *(const bf16x8*)(sx1 + aoff[mt] + ks * 32);
#pragma unroll
        for (int mt = 0; mt < 4; mt++)
#pragma unroll
            for (int nt = 0; nt < 2; nt++)
                acc2[mt][nt] = __builtin_amdgcn_mfma_f32_16x16x32_bf16(av2[mt], bv2[nt], acc2[mt][nt], 0, 0, 0);
    }

    // ---------------- Phase E: relu+bias -> x2 bf16 (overlay) ----------------
    __syncthreads();               // all layer-2 reads of x1 done
    unsigned short* sx2 = sH;      // [64][140] (70 dw stride, gcd 2 -> free)
#pragma unroll
    for (int mt = 0; mt < 4; mt++)
#pragma unroll
        for (int nt = 0; nt < 2; nt++)
#pragma unroll
            for (int i = 0; i < 4; i++) {
                int row = mt * 16 + quad * 4 + i;
                int col = nb2 + nt * 16 + lrow;
                float v = acc2[mt][nt][i] + b2v[nt];
                v = v > 0.f ? v : 0.f;
                sx2[row * 140 + col] = cvt1(v);
            }
    __syncthreads();

    // ---------------- Phase F: layer 3 (N=2), half-dots + shfl ----------------
    {
        int r = t >> 2;            // edge row 0..63
        int c = t & 1;             // class
        int h = (t >> 1) & 1;      // K-half
        const unsigned short* xr = sx2 + r * 140 + h * 64;
        const float* w3c = sW3 + c * 128 + h * 64;
        float s = 0.f;
#pragma unroll
        for (int j = 0; j < 8; j++) {
            uint4 v = *(const uint4*)(xr + j * 8);
            f32x4 w0 = *(const f32x4*)(w3c + j * 8);
            f32x4 w1 = *(const f32x4*)(w3c + j * 8 + 4);
            s += bflo(v.x) * w0[0] + bfhi(v.x) * w0[1]
               + bflo(v.y) * w0[2] + bfhi(v.y) * w0[3]
               + bflo(v.z) * w1[0] + bfhi(v.z) * w1[1]
               + bflo(v.w) * w1[2] + bfhi(v.w) * w1[3];
        }
        s += __shfl_xor(s, 2);     // combine K-halves
        int e = e0 + r;
        if (h == 0 && e < E) out[e * 2 + c] = s + b3[c];
    }
}

extern "C" void kernel_launch(void* const* d_in, const int* in_sizes, int n_in,
                              void* d_out, int out_size, void* d_ws, size_t ws_size,
                              hipStream_t stream) {
    const float* node = (const float*)d_in[0];
    const int* src    = (const int*)d_in[1];
    const int* dst    = (const int*)d_in[2];
    const float* W1   = (const float*)d_in[3];
    const float* b1   = (const float*)d_in[4];
    const float* W2   = (const float*)d_in[5];
    const float* b2   = (const float*)d_in[6];
    const float* W3   = (const float*)d_in[7];
    const float* b3   = (const float*)d_in[8];
    float* out = (float*)d_out;
    const int NN = in_sizes[0] / H;                    // 50000 nodes
    const int E = in_sizes[1];

    unsigned short* W1P = (unsigned short*)d_ws;       // packed W1, 256 KiB
    unsigned short* W2P = W1P + 512 * 256;             // packed W2, 64 KiB
    unsigned short* NBF = W2P + 256 * 128;             // [N][128] bf16, 12.8 MB

    hipLaunchKernelGGL(prep_node, dim3((NN * H / 4 + 255) / 256), dim3(256), 0, stream, node, NBF);
    hipLaunchKernelGGL(prep_w1, dim3(512), dim3(256), 0, stream, W1, W1P);
    hipLaunchKernelGGL(prep_w2, dim3(128), dim3(256), 0, stream, W2, W2P);
    const int nblk = (E + 63) / 64;
    hipLaunchKernelGGL(fused_mlp, dim3(nblk), dim3(256), 0, stream,
                       NBF, src, dst, W1P, b1, W2P, b2, W3, b3, out, E);
}